// Round 1
// baseline (1931.718 us; speedup 1.0000x reference)
//
#include <hip/hip_runtime.h>
#include <stdint.h>

// Problem constants (from reference): scores [1,128,768,768] f32, k=500.
#define CNUM 128
#define H 768
#define W 768
#define HW (H*W)
#define KSEL 500
#define NB 8192          // histogram buckets = top 13 bits of sortable float
#define CAP 2048         // per-channel candidate buffer capacity

// Workspace layout (bytes):
//   [0, HIST_BYTES)            per-channel histograms  (CNUM * NB * 4 = 4 MiB)
//   [CNT_OFF, +CNUM*4)         per-channel candidate counters
//   [THR_OFF, +CNUM*4)         per-channel score-bit thresholds
//   [CAND_OFF, +CNUM*CAP*8)    per-channel candidate keys (u64)
static const size_t HIST_BYTES = (size_t)CNUM * NB * 4;      // 4,194,304
static const size_t CNT_OFF    = HIST_BYTES;                 // 4,194,304
static const size_t THR_OFF    = CNT_OFF + CNUM * 4;         // 4,194,816
static const size_t CAND_OFF   = THR_OFF + CNUM * 4;         // 4,195,328 (8-aligned)

__device__ __forceinline__ unsigned f2sort(float f) {
    unsigned b = __float_as_uint(f);
    return (b & 0x80000000u) ? ~b : (b | 0x80000000u);
}

__global__ __launch_bounds__(256) void k_init(unsigned* __restrict__ p, int n) {
    int i = blockIdx.x * 256 + threadIdx.x;
    int stride = gridDim.x * 256;
    for (; i < n; i += stride) p[i] = 0u;
}

// Local-max test shared by k_hist / k_collect.
__device__ __forceinline__ bool is_local_max(const float* __restrict__ ch,
                                             int y, int x, int idx, float v) {
    float m = -3.402823466e38f;
    bool up = y > 0, dn = y < H - 1, lf = x > 0, rt = x < W - 1;
    if (lf) m = fmaxf(m, ch[idx - 1]);
    if (rt) m = fmaxf(m, ch[idx + 1]);
    if (up) {
        m = fmaxf(m, ch[idx - W]);
        if (lf) m = fmaxf(m, ch[idx - W - 1]);
        if (rt) m = fmaxf(m, ch[idx - W + 1]);
    }
    if (dn) {
        m = fmaxf(m, ch[idx + W]);
        if (lf) m = fmaxf(m, ch[idx + W - 1]);
        if (rt) m = fmaxf(m, ch[idx + W + 1]);
    }
    return v >= m;
}

// Pass 1: per-channel histogram of sortable score bits over NMS survivors.
__global__ __launch_bounds__(256) void k_hist(const float* __restrict__ S,
                                              unsigned* __restrict__ hist) {
    const int c = blockIdx.y;
    const int r0 = blockIdx.x * 8;
    const float* ch = S + (size_t)c * HW;
    unsigned* h = hist + (size_t)c * NB;
    for (int p = threadIdx.x; p < 8 * W; p += 256) {
        int y = r0 + p / W;
        int x = p % W;
        int idx = y * W + x;
        float v = ch[idx];
        if (is_local_max(ch, y, x, idx, v)) {
            atomicAdd(&h[f2sort(v) >> 19], 1u);
        }
    }
}

// Pass 2: per-channel threshold = lower bound of the bucket containing the
// KSEL-th largest candidate (scanning buckets from the top).
__global__ __launch_bounds__(256) void k_thresh(const unsigned* __restrict__ hist,
                                                unsigned* __restrict__ thresh) {
    const int c = blockIdx.x;
    const unsigned* h = hist + (size_t)c * NB;
    __shared__ unsigned hs[NB];
    __shared__ unsigned tsum[256];
    for (int i = threadIdx.x; i < NB; i += 256) hs[i] = h[i];
    __syncthreads();
    unsigned local = 0;
    int base = threadIdx.x * (NB / 256);
    for (int i = 0; i < NB / 256; ++i) local += hs[base + i];
    tsum[threadIdx.x] = local;
    __syncthreads();
    if (threadIdx.x == 0) {
        unsigned cum = 0, cum_before = 0;
        int sel = -1;
        for (int i = 255; i >= 0; --i) {
            if (sel < 0 && cum + tsum[i] >= KSEL) { sel = i; cum_before = cum; }
            cum += tsum[i];
        }
        int T = 0;
        if (sel >= 0) {
            unsigned c2 = cum_before;
            for (int b = sel * (NB / 256) + (NB / 256) - 1; b >= sel * (NB / 256); --b) {
                c2 += hs[b];
                if (c2 >= KSEL) { T = b; break; }
            }
        }
        thresh[c] = (unsigned)T << 19;
    }
}

// Pass 3: recompute NMS, collect candidates >= threshold into small buffers.
__global__ __launch_bounds__(256) void k_collect(const float* __restrict__ S,
                                                 const unsigned* __restrict__ thresh,
                                                 unsigned* __restrict__ cnt,
                                                 unsigned long long* __restrict__ cand) {
    const int c = blockIdx.y;
    const int r0 = blockIdx.x * 8;
    const float* ch = S + (size_t)c * HW;
    const unsigned th = thresh[c];
    unsigned long long* cc = cand + (size_t)c * CAP;
    for (int p = threadIdx.x; p < 8 * W; p += 256) {
        int y = r0 + p / W;
        int x = p % W;
        int idx = y * W + x;
        float v = ch[idx];
        unsigned u = f2sort(v);
        if (u >= th && is_local_max(ch, y, x, idx, v)) {
            unsigned pos = atomicAdd(&cnt[c], 1u);
            if (pos < CAP) {
                cc[pos] = ((unsigned long long)u << 32) | (unsigned)(0xFFFFFFFFu - (unsigned)idx);
            }
        }
    }
}

// Pass 4: per-channel bitonic sort (descending) of CAP keys in LDS; emit
// top-KSEL x, y, score.  Key = (sortable_score<<32) | (~idx) reproduces
// lax.top_k order incl. lower-index-first tie-break.
__global__ __launch_bounds__(256) void k_sort(const unsigned* __restrict__ cnt,
                                              const unsigned long long* __restrict__ cand,
                                              float* __restrict__ out) {
    const int c = blockIdx.x;
    __shared__ unsigned long long keys[CAP];
    unsigned n = cnt[c];
    if (n > CAP) n = CAP;
    const unsigned long long* cc = cand + (size_t)c * CAP;
    for (int i = threadIdx.x; i < CAP; i += 256)
        keys[i] = (i < (int)n) ? cc[i] : 0ull;
    __syncthreads();
    for (int kk = 2; kk <= CAP; kk <<= 1) {
        for (int j = kk >> 1; j > 0; j >>= 1) {
            for (int i = threadIdx.x; i < CAP; i += 256) {
                int ixj = i ^ j;
                if (ixj > i) {
                    unsigned long long a = keys[i], b = keys[ixj];
                    bool desc = ((i & kk) == 0);
                    if (desc ? (a < b) : (a > b)) { keys[i] = b; keys[ixj] = a; }
                }
            }
            __syncthreads();
        }
    }
    for (int i = threadIdx.x; i < KSEL; i += 256) {
        unsigned long long key = keys[i];
        unsigned u = (unsigned)(key >> 32);
        unsigned idx = 0xFFFFFFFFu - (unsigned)(key & 0xFFFFFFFFu);
        unsigned bits = (u & 0x80000000u) ? (u ^ 0x80000000u) : ~u;
        float score = __uint_as_float(bits);
        float fx = (float)(idx % W);
        float fy = (float)(idx / W);
        out[c * KSEL + i] = fx;                          // keypoints[0,c,i]
        out[CNUM * KSEL + c * KSEL + i] = fy;            // keypoints[1,c,i]
        out[2 * CNUM * KSEL + c * KSEL + i] = score;     // scores[c,i]
    }
}

extern "C" void kernel_launch(void* const* d_in, const int* in_sizes, int n_in,
                              void* d_out, int out_size, void* d_ws, size_t ws_size,
                              hipStream_t stream) {
    const float* S = (const float*)d_in[0];   // scores, f32, [1,128,768,768]
    // d_in[1] is the python scalar k=500; compile-time KSEL.
    float* out = (float*)d_out;
    unsigned char* ws = (unsigned char*)d_ws;
    unsigned* hist = (unsigned*)ws;
    unsigned* cnt  = (unsigned*)(ws + CNT_OFF);
    unsigned* thr  = (unsigned*)(ws + THR_OFF);
    unsigned long long* cand = (unsigned long long*)(ws + CAND_OFF);

    // zero hist + counters (ws is poisoned 0xAA before every timed call)
    k_init<<<2048, 256, 0, stream>>>((unsigned*)ws, (int)(THR_OFF / 4));
    k_hist<<<dim3(H / 8, CNUM), 256, 0, stream>>>(S, hist);
    k_thresh<<<CNUM, 256, 0, stream>>>(hist, thr);
    k_collect<<<dim3(H / 8, CNUM), 256, 0, stream>>>(S, thr, cnt, cand);
    k_sort<<<CNUM, 256, 0, stream>>>(cnt, cand, out);
}

// Round 3
// 1743.825 us; speedup vs baseline: 1.1077x; 1.1077x over previous
//
#include <hip/hip_runtime.h>
#include <stdint.h>

// Problem constants (from reference): scores [1,128,768,768] f32, k=500.
#define CNUM 128
#define H 768
#define W 768
#define HW (H*W)
#define KSEL 500
#define NB 8192          // histogram buckets = top 13 bits of sortable float
#define CAP 2048         // per-channel candidate buffer capacity
#define HBLK 16          // histogram blocks per channel
#define ROWS_PER_BLK (H / HBLK)   // 48

// Workspace layout (bytes):
//   [0, HIST_BYTES)            per-channel histograms  (CNUM * NB * 4 = 4 MiB)
//   [CNT_OFF, +CNUM*4)         per-channel candidate counters
//   [THR_OFF, +CNUM*4)         per-channel score-bit thresholds
//   [CAND_OFF, +CNUM*CAP*8)    per-channel candidate keys (u64)
static const size_t HIST_BYTES = (size_t)CNUM * NB * 4;      // 4,194,304
static const size_t CNT_OFF    = HIST_BYTES;                 // 4,194,304
static const size_t THR_OFF    = CNT_OFF + CNUM * 4;         // 4,194,816
static const size_t CAND_OFF   = THR_OFF + CNUM * 4;         // 4,195,328 (8-aligned)

__device__ __forceinline__ unsigned f2sort(float f) {
    unsigned b = __float_as_uint(f);
    return (b & 0x80000000u) ? ~b : (b | 0x80000000u);
}

__global__ __launch_bounds__(256) void k_init(unsigned* __restrict__ p, int n) {
    int i = blockIdx.x * 256 + threadIdx.x;
    int stride = gridDim.x * 256;
    for (; i < n; i += stride) p[i] = 0u;
}

// Local-max test shared by k_hist / k_collect.
__device__ __forceinline__ bool is_local_max(const float* __restrict__ ch,
                                             int y, int x, int idx, float v) {
    float m = -3.402823466e38f;
    bool up = y > 0, dn = y < H - 1, lf = x > 0, rt = x < W - 1;
    if (lf) m = fmaxf(m, ch[idx - 1]);
    if (rt) m = fmaxf(m, ch[idx + 1]);
    if (up) {
        m = fmaxf(m, ch[idx - W]);
        if (lf) m = fmaxf(m, ch[idx - W - 1]);
        if (rt) m = fmaxf(m, ch[idx - W + 1]);
    }
    if (dn) {
        m = fmaxf(m, ch[idx + W]);
        if (lf) m = fmaxf(m, ch[idx + W - 1]);
        if (rt) m = fmaxf(m, ch[idx + W + 1]);
    }
    return v >= m;
}

// Pass 1: per-channel histogram of sortable score bits over NMS survivors.
// LDS-privatized per block (16 blocks/channel), flushed with one global
// atomic per NONZERO bucket -> kills the round-1 global-atomic contention.
__global__ __launch_bounds__(256) void k_hist(const float* __restrict__ S,
                                              unsigned* __restrict__ hist) {
    __shared__ unsigned hs[NB];
    for (int i = threadIdx.x; i < NB; i += 256) hs[i] = 0u;
    __syncthreads();

    const int c = blockIdx.y;
    const int r0 = blockIdx.x * ROWS_PER_BLK;
    const float* ch = S + (size_t)c * HW;
    for (int p = threadIdx.x; p < ROWS_PER_BLK * W; p += 256) {
        int y = r0 + p / W;
        int x = p % W;
        int idx = y * W + x;
        float v = ch[idx];
        if (is_local_max(ch, y, x, idx, v)) {
            atomicAdd(&hs[f2sort(v) >> 19], 1u);
        }
    }
    __syncthreads();

    unsigned* h = hist + (size_t)c * NB;
    for (int i = threadIdx.x; i < NB; i += 256) {
        unsigned v = hs[i];
        if (v) atomicAdd(&h[i], v);
    }
}

// Pass 2: per-channel threshold = lower bound of the bucket containing the
// KSEL-th largest candidate (scanning buckets from the top).
__global__ __launch_bounds__(256) void k_thresh(const unsigned* __restrict__ hist,
                                                unsigned* __restrict__ thresh) {
    const int c = blockIdx.x;
    const unsigned* h = hist + (size_t)c * NB;
    __shared__ unsigned hs[NB];
    __shared__ unsigned tsum[256];
    for (int i = threadIdx.x; i < NB; i += 256) hs[i] = h[i];
    __syncthreads();
    unsigned local = 0;
    int base = threadIdx.x * (NB / 256);
    for (int i = 0; i < NB / 256; ++i) local += hs[base + i];
    tsum[threadIdx.x] = local;
    __syncthreads();
    if (threadIdx.x == 0) {
        unsigned cum = 0, cum_before = 0;
        int sel = -1;
        for (int i = 255; i >= 0; --i) {
            if (sel < 0 && cum + tsum[i] >= KSEL) { sel = i; cum_before = cum; }
            cum += tsum[i];
        }
        int T = 0;
        if (sel >= 0) {
            unsigned c2 = cum_before;
            for (int b = sel * (NB / 256) + (NB / 256) - 1; b >= sel * (NB / 256); --b) {
                c2 += hs[b];
                if (c2 >= KSEL) { T = b; break; }
            }
        }
        thresh[c] = (unsigned)T << 19;
    }
}

// Pass 3: recompute NMS, collect candidates >= threshold into small buffers.
// Threshold test FIRST (pass rate ~0.1%) so this is a pure streaming read.
__global__ __launch_bounds__(256) void k_collect(const float* __restrict__ S,
                                                 const unsigned* __restrict__ thresh,
                                                 unsigned* __restrict__ cnt,
                                                 unsigned long long* __restrict__ cand) {
    const int c = blockIdx.y;
    const int r0 = blockIdx.x * 8;
    const float* ch = S + (size_t)c * HW;
    const unsigned th = thresh[c];
    unsigned long long* cc = cand + (size_t)c * CAP;
    for (int p = threadIdx.x; p < 8 * W; p += 256) {
        int y = r0 + p / W;
        int x = p % W;
        int idx = y * W + x;
        float v = ch[idx];
        unsigned u = f2sort(v);
        if (u >= th && is_local_max(ch, y, x, idx, v)) {
            unsigned pos = atomicAdd(&cnt[c], 1u);
            if (pos < CAP) {
                cc[pos] = ((unsigned long long)u << 32) | (unsigned)(0xFFFFFFFFu - (unsigned)idx);
            }
        }
    }
}

// Pass 4: per-channel bitonic sort (descending) of CAP keys in LDS; emit
// top-KSEL x, y, score.  Key = (sortable_score<<32) | (~idx) reproduces
// lax.top_k order incl. lower-index-first tie-break.
__global__ __launch_bounds__(256) void k_sort(const unsigned* __restrict__ cnt,
                                              const unsigned long long* __restrict__ cand,
                                              float* __restrict__ out) {
    const int c = blockIdx.x;
    __shared__ unsigned long long keys[CAP];
    unsigned n = cnt[c];
    if (n > CAP) n = CAP;
    const unsigned long long* cc = cand + (size_t)c * CAP;
    for (int i = threadIdx.x; i < CAP; i += 256)
        keys[i] = (i < (int)n) ? cc[i] : 0ull;
    __syncthreads();
    for (int kk = 2; kk <= CAP; kk <<= 1) {
        for (int j = kk >> 1; j > 0; j >>= 1) {
            for (int i = threadIdx.x; i < CAP; i += 256) {
                int ixj = i ^ j;
                if (ixj > i) {
                    unsigned long long a = keys[i], b = keys[ixj];
                    bool desc = ((i & kk) == 0);
                    if (desc ? (a < b) : (a > b)) { keys[i] = b; keys[ixj] = a; }
                }
            }
            __syncthreads();
        }
    }
    for (int i = threadIdx.x; i < KSEL; i += 256) {
        unsigned long long key = keys[i];
        unsigned u = (unsigned)(key >> 32);
        unsigned idx = 0xFFFFFFFFu - (unsigned)(key & 0xFFFFFFFFu);
        unsigned bits = (u & 0x80000000u) ? (u ^ 0x80000000u) : ~u;
        float score = __uint_as_float(bits);
        float fx = (float)(idx % W);
        float fy = (float)(idx / W);
        out[c * KSEL + i] = fx;                          // keypoints[0,c,i]
        out[CNUM * KSEL + c * KSEL + i] = fy;            // keypoints[1,c,i]
        out[2 * CNUM * KSEL + c * KSEL + i] = score;     // scores[c,i]
    }
}

extern "C" void kernel_launch(void* const* d_in, const int* in_sizes, int n_in,
                              void* d_out, int out_size, void* d_ws, size_t ws_size,
                              hipStream_t stream) {
    const float* S = (const float*)d_in[0];   // scores, f32, [1,128,768,768]
    // d_in[1] is the python scalar k=500; compile-time KSEL.
    float* out = (float*)d_out;
    unsigned char* ws = (unsigned char*)d_ws;
    unsigned* hist = (unsigned*)ws;
    unsigned* cnt  = (unsigned*)(ws + CNT_OFF);
    unsigned* thr  = (unsigned*)(ws + THR_OFF);
    unsigned long long* cand = (unsigned long long*)(ws + CAND_OFF);

    // zero hist + counters (ws is poisoned 0xAA before every timed call)
    k_init<<<2048, 256, 0, stream>>>((unsigned*)ws, (int)(THR_OFF / 4));
    k_hist<<<dim3(HBLK, CNUM), 256, 0, stream>>>(S, hist);
    k_thresh<<<CNUM, 256, 0, stream>>>(hist, thr);
    k_collect<<<dim3(H / 8, CNUM), 256, 0, stream>>>(S, thr, cnt, cand);
    k_sort<<<CNUM, 256, 0, stream>>>(cnt, cand, out);
}

// Round 4
// 1027.681 us; speedup vs baseline: 1.8797x; 1.6969x over previous
//
#include <hip/hip_runtime.h>
#include <stdint.h>

// Problem constants (from reference): scores [1,128,768,768] f32, k=500.
#define CNUM 128
#define H 768
#define W 768
#define HW (H*W)
#define KSEL 500
#define NB 8192          // histogram buckets = top 13 bits of sortable float
#define CAP 2048         // per-channel candidate buffer capacity
#define HBLK 16          // row-strips per channel in k_hist
#define ROWS_PER_BLK (H / HBLK)   // 48
#define NEG_INF (-3.402823466e38f)

// Workspace layout (bytes):
static const size_t HIST_BYTES = (size_t)CNUM * NB * 4;      // 4,194,304
static const size_t CNT_OFF    = HIST_BYTES;
static const size_t THR_OFF    = CNT_OFF + CNUM * 4;
static const size_t CAND_OFF   = THR_OFF + CNUM * 4;         // 8-aligned

__device__ __forceinline__ unsigned f2sort(float f) {
    unsigned b = __float_as_uint(f);
    return (b & 0x80000000u) ? ~b : (b | 0x80000000u);
}
__device__ __forceinline__ float max3f(float a, float b, float c) {
    return fmaxf(fmaxf(a, b), c);
}

__global__ __launch_bounds__(256) void k_init(unsigned* __restrict__ p, int n) {
    int i = blockIdx.x * 256 + threadIdx.x;
    int stride = gridDim.x * 256;
    for (; i < n; i += stride) p[i] = 0u;
}

// Scalar 8-neighbor local-max test (only used on rare threshold-passers).
__device__ __forceinline__ bool is_local_max(const float* __restrict__ ch,
                                             int y, int x, int idx, float v) {
    float m = NEG_INF;
    bool up = y > 0, dn = y < H - 1, lf = x > 0, rt = x < W - 1;
    if (lf) m = fmaxf(m, ch[idx - 1]);
    if (rt) m = fmaxf(m, ch[idx + 1]);
    if (up) {
        m = fmaxf(m, ch[idx - W]);
        if (lf) m = fmaxf(m, ch[idx - W - 1]);
        if (rt) m = fmaxf(m, ch[idx - W + 1]);
    }
    if (dn) {
        m = fmaxf(m, ch[idx + W]);
        if (lf) m = fmaxf(m, ch[idx + W - 1]);
        if (rt) m = fmaxf(m, ch[idx + W + 1]);
    }
    return v >= m;
}

// Pass 1: NMS + per-channel histogram, rolling 3-row register window.
// 192 threads = 3 waves; wave w owns columns [w*256, w*256+256) as 64 lanes
// x float4. One dwordx4 load per row per lane (+2 predicated halo scalars),
// separable max3 (vertical in-register, horizontal via register neighbors +
// 2 shuffles). LDS hist packed 2 x u16 per u32 word (16 KB).
__global__ __launch_bounds__(192) void k_hist(const float* __restrict__ S,
                                              unsigned* __restrict__ hist) {
    __shared__ unsigned hs32[NB / 2];
    for (int i = threadIdx.x; i < NB / 2; i += 192) hs32[i] = 0u;
    __syncthreads();

    const int c = blockIdx.y;
    const int r0 = blockIdx.x * ROWS_PER_BLK;
    const int wid = threadIdx.x >> 6;          // 0..2 (column strip)
    const int lane = threadIdx.x & 63;
    const int x0 = wid * 256 + lane * 4;
    const float* ch = S + (size_t)c * HW;

    const bool has_l = (wid > 0);              // strip-left halo exists
    const bool has_r = (wid < 2);              // strip-right halo exists

    float4 v0, v1, v2;
    float hl0, hl1, hl2, hr0, hr1, hr2;

    // init rows r0-1 and r0
    if (r0 > 0) {
        v0 = *(const float4*)(ch + (r0 - 1) * W + x0);
        hl0 = (lane == 0 && has_l) ? ch[(r0 - 1) * W + x0 - 1] : NEG_INF;
        hr0 = (lane == 63 && has_r) ? ch[(r0 - 1) * W + x0 + 4] : NEG_INF;
    } else {
        v0 = make_float4(NEG_INF, NEG_INF, NEG_INF, NEG_INF);
        hl0 = NEG_INF; hr0 = NEG_INF;
    }
    v1 = *(const float4*)(ch + r0 * W + x0);
    hl1 = (lane == 0 && has_l) ? ch[r0 * W + x0 - 1] : NEG_INF;
    hr1 = (lane == 63 && has_r) ? ch[r0 * W + x0 + 4] : NEG_INF;

    for (int y = r0; y < r0 + ROWS_PER_BLK; ++y) {
        const int yn = y + 1;
        if (yn < H) {
            v2 = *(const float4*)(ch + yn * W + x0);
            hl2 = (lane == 0 && has_l) ? ch[yn * W + x0 - 1] : NEG_INF;
            hr2 = (lane == 63 && has_r) ? ch[yn * W + x0 + 4] : NEG_INF;
        } else {
            v2 = make_float4(NEG_INF, NEG_INF, NEG_INF, NEG_INF);
            hl2 = NEG_INF; hr2 = NEG_INF;
        }
        // vertical max over rows y-1..y+1, per column
        float vm0 = max3f(v0.x, v1.x, v2.x);
        float vm1 = max3f(v0.y, v1.y, v2.y);
        float vm2 = max3f(v0.z, v1.z, v2.z);
        float vm3 = max3f(v0.w, v1.w, v2.w);
        float hvl = max3f(hl0, hl1, hl2);
        float hvr = max3f(hr0, hr1, hr2);
        // horizontal neighbors across lanes
        float vmL = __shfl_up(vm3, 1);   // lane i <- lane i-1's vm3
        float vmR = __shfl_down(vm0, 1); // lane i <- lane i+1's vm0
        if (lane == 0)  vmL = hvl;
        if (lane == 63) vmR = hvr;
        // 3x3 pooled max (includes center) per column
        float p0 = max3f(vmL, vm0, vm1);
        float p1 = max3f(vm0, vm1, vm2);
        float p2 = max3f(vm1, vm2, vm3);
        float p3 = max3f(vm2, vm3, vmR);
        // survivors: center == pooled  <=>  center >= pooled
        if (v1.x >= p0) { unsigned b = f2sort(v1.x) >> 19; atomicAdd(&hs32[b >> 1], 1u << ((b & 1) * 16)); }
        if (v1.y >= p1) { unsigned b = f2sort(v1.y) >> 19; atomicAdd(&hs32[b >> 1], 1u << ((b & 1) * 16)); }
        if (v1.z >= p2) { unsigned b = f2sort(v1.z) >> 19; atomicAdd(&hs32[b >> 1], 1u << ((b & 1) * 16)); }
        if (v1.w >= p3) { unsigned b = f2sort(v1.w) >> 19; atomicAdd(&hs32[b >> 1], 1u << ((b & 1) * 16)); }
        // rotate window
        v0 = v1; v1 = v2;
        hl0 = hl1; hl1 = hl2;
        hr0 = hr1; hr1 = hr2;
    }

    __syncthreads();
    unsigned* h = hist + (size_t)c * NB;
    for (int i = threadIdx.x; i < NB / 2; i += 192) {
        unsigned w = hs32[i];
        unsigned c0 = w & 0xFFFFu, c1 = w >> 16;
        if (c0) atomicAdd(&h[2 * i], c0);
        if (c1) atomicAdd(&h[2 * i + 1], c1);
    }
}

// Pass 2: per-channel threshold = lower bound of the bucket containing the
// KSEL-th largest candidate (scanning buckets from the top).
__global__ __launch_bounds__(256) void k_thresh(const unsigned* __restrict__ hist,
                                                unsigned* __restrict__ thresh) {
    const int c = blockIdx.x;
    const unsigned* h = hist + (size_t)c * NB;
    __shared__ unsigned hs[NB];
    __shared__ unsigned tsum[256];
    for (int i = threadIdx.x; i < NB; i += 256) hs[i] = h[i];
    __syncthreads();
    unsigned local = 0;
    int base = threadIdx.x * (NB / 256);
    for (int i = 0; i < NB / 256; ++i) local += hs[base + i];
    tsum[threadIdx.x] = local;
    __syncthreads();
    if (threadIdx.x == 0) {
        unsigned cum = 0, cum_before = 0;
        int sel = -1;
        for (int i = 255; i >= 0; --i) {
            if (sel < 0 && cum + tsum[i] >= KSEL) { sel = i; cum_before = cum; }
            cum += tsum[i];
        }
        int T = 0;
        if (sel >= 0) {
            unsigned c2 = cum_before;
            for (int b = sel * (NB / 256) + (NB / 256) - 1; b >= sel * (NB / 256); --b) {
                c2 += hs[b];
                if (c2 >= KSEL) { T = b; break; }
            }
        }
        thresh[c] = (unsigned)T << 19;
    }
}

// Pass 3: threshold-first streaming collect. One float4 load per 4 pixels;
// only lanes whose sortable bits pass `th` (~0.34%) run the 8-neighbor check.
__global__ __launch_bounds__(256) void k_collect(const float* __restrict__ S,
                                                 const unsigned* __restrict__ thresh,
                                                 unsigned* __restrict__ cnt,
                                                 unsigned long long* __restrict__ cand) {
    const int c = blockIdx.y;
    const float* ch = S + (size_t)c * HW;
    const unsigned th = thresh[c];
    unsigned long long* cc = cand + (size_t)c * CAP;
    const int base = blockIdx.x * 256 + threadIdx.x;   // gridDim.x = 144
    #pragma unroll
    for (int t = 0; t < 4; ++t) {
        int i4 = base + t * (144 * 256);               // 4*144*256 = HW/4
        float4 v = *(const float4*)(ch + (size_t)i4 * 4);
        unsigned u0 = f2sort(v.x), u1 = f2sort(v.y), u2 = f2sort(v.z), u3 = f2sort(v.w);
        bool q0 = u0 >= th, q1 = u1 >= th, q2 = u2 >= th, q3 = u3 >= th;
        if (q0 | q1 | q2 | q3) {
            int p = i4 * 4;
            int y = p / W;
            int x = p - y * W;          // float4 never crosses a row (W%4==0)
            float vv[4] = {v.x, v.y, v.z, v.w};
            unsigned uu[4] = {u0, u1, u2, u3};
            #pragma unroll
            for (int j = 0; j < 4; ++j) {
                if (uu[j] >= th && is_local_max(ch, y, x + j, p + j, vv[j])) {
                    unsigned pos = atomicAdd(&cnt[c], 1u);
                    if (pos < CAP) {
                        cc[pos] = ((unsigned long long)uu[j] << 32)
                                | (unsigned)(0xFFFFFFFFu - (unsigned)(p + j));
                    }
                }
            }
        }
    }
}

// Pass 4: per-channel bitonic sort (descending) of CAP keys in LDS; emit
// top-KSEL x, y, score.  Key = (sortable_score<<32) | (~idx) reproduces
// lax.top_k order incl. lower-index-first tie-break.
__global__ __launch_bounds__(256) void k_sort(const unsigned* __restrict__ cnt,
                                              const unsigned long long* __restrict__ cand,
                                              float* __restrict__ out) {
    const int c = blockIdx.x;
    __shared__ unsigned long long keys[CAP];
    unsigned n = cnt[c];
    if (n > CAP) n = CAP;
    const unsigned long long* cc = cand + (size_t)c * CAP;
    for (int i = threadIdx.x; i < CAP; i += 256)
        keys[i] = (i < (int)n) ? cc[i] : 0ull;
    __syncthreads();
    for (int kk = 2; kk <= CAP; kk <<= 1) {
        for (int j = kk >> 1; j > 0; j >>= 1) {
            for (int i = threadIdx.x; i < CAP; i += 256) {
                int ixj = i ^ j;
                if (ixj > i) {
                    unsigned long long a = keys[i], b = keys[ixj];
                    bool desc = ((i & kk) == 0);
                    if (desc ? (a < b) : (a > b)) { keys[i] = b; keys[ixj] = a; }
                }
            }
            __syncthreads();
        }
    }
    for (int i = threadIdx.x; i < KSEL; i += 256) {
        unsigned long long key = keys[i];
        unsigned u = (unsigned)(key >> 32);
        unsigned idx = 0xFFFFFFFFu - (unsigned)(key & 0xFFFFFFFFu);
        unsigned bits = (u & 0x80000000u) ? (u ^ 0x80000000u) : ~u;
        float score = __uint_as_float(bits);
        float fx = (float)(idx % W);
        float fy = (float)(idx / W);
        out[c * KSEL + i] = fx;                          // keypoints[0,c,i]
        out[CNUM * KSEL + c * KSEL + i] = fy;            // keypoints[1,c,i]
        out[2 * CNUM * KSEL + c * KSEL + i] = score;     // scores[c,i]
    }
}

extern "C" void kernel_launch(void* const* d_in, const int* in_sizes, int n_in,
                              void* d_out, int out_size, void* d_ws, size_t ws_size,
                              hipStream_t stream) {
    const float* S = (const float*)d_in[0];   // scores, f32, [1,128,768,768]
    float* out = (float*)d_out;
    unsigned char* ws = (unsigned char*)d_ws;
    unsigned* hist = (unsigned*)ws;
    unsigned* cnt  = (unsigned*)(ws + CNT_OFF);
    unsigned* thr  = (unsigned*)(ws + THR_OFF);
    unsigned long long* cand = (unsigned long long*)(ws + CAND_OFF);

    k_init<<<2048, 256, 0, stream>>>((unsigned*)ws, (int)(THR_OFF / 4));
    k_hist<<<dim3(HBLK, CNUM), 192, 0, stream>>>(S, hist);
    k_thresh<<<CNUM, 256, 0, stream>>>(hist, thr);
    k_collect<<<dim3(144, CNUM), 256, 0, stream>>>(S, thr, cnt, cand);
    k_sort<<<CNUM, 256, 0, stream>>>(cnt, cand, out);
}